// Round 2
// baseline (989.590 us; speedup 1.0000x reference)
//
#include <hip/hip_runtime.h>

typedef unsigned short u16;
typedef unsigned int   u32;

// ---- bf16 helpers (bf16 = top 16 bits of fp32) ----
__device__ __forceinline__ float bl(u32 u){ union{u32 i; float f;} c; c.i = u << 16; return c.f; }
__device__ __forceinline__ float bh(u32 u){ union{u32 i; float f;} c; c.i = u & 0xffff0000u; return c.f; }
__device__ __forceinline__ float b2f(u16 v){ union{u32 i; float f;} c; c.i = ((u32)v) << 16; return c.f; }
__device__ __forceinline__ u16 f2b(float f){
  union{float f; u32 i;} c; c.f = f;
  u32 i = c.i;
  u32 r = (i + 0x7fffu + ((i >> 16) & 1u)) >> 16;  // RNE
  return (u16)r;
}
__device__ __forceinline__ u32 pk2(float a, float b){
  return (u32)f2b(a) | ((u32)f2b(b) << 16);
}
__device__ __forceinline__ void store16bf(u16* dst, const float* v){
  uint4 q;
  q.x = pk2(v[0], v[1]);  q.y = pk2(v[2], v[3]);
  q.z = pk2(v[4], v[5]);  q.w = pk2(v[6], v[7]);
  ((uint4*)dst)[0] = q;
  q.x = pk2(v[8], v[9]);  q.y = pk2(v[10], v[11]);
  q.z = pk2(v[12], v[13]); q.w = pk2(v[14], v[15]);
  ((uint4*)dst)[1] = q;
}

// =====================================================================
// Kernel 1: x_enc = PReLU(x) @ W_enc    (fp32 in, bf16 xenc out)
//           agg   = x_enc + e1[5] + e2[0]   (self-loop init, fp32)
// blockIdx.y = col-half (64 cols). 64 rows/block, 256 thr.
// LDS: sW 32KB fp32 + sX 33.8KB fp32.
// =====================================================================
__global__ __launch_bounds__(256) void k_enc(
    const float* __restrict__ x, const float* __restrict__ pa,
    const float* __restrict__ Wenc, const float* __restrict__ e1,
    const float* __restrict__ e2, u16* __restrict__ xenc,
    float* __restrict__ agg, int N)
{
  __shared__ float sW[128 * 64];      // 32 KB  (col-half of W_enc)
  __shared__ float sX[64][132];       // 33.8 KB, padded
  __shared__ float sLoop[64];

  const int t  = threadIdx.x;
  const int ch = blockIdx.y;          // 0/1 -> cols ch*64 .. +63
  // stage W_enc half: 128 rows x 64 cols = 2048 float4
  #pragma unroll
  for (int j = 0; j < 8; j++) {
    int i = t + 256 * j;
    int row = i >> 4, c4 = i & 15;
    *(float4*)&sW[row * 64 + c4 * 4] =
        *(const float4*)&Wenc[row * 128 + ch * 64 + c4 * 4];
  }
  if (t < 64) sLoop[t] = e1[5 * 128 + ch * 64 + t] + e2[ch * 64 + t];
  const float slope = pa[0];

  const int r0 = blockIdx.x * 64;
  // stage 64 x-rows with PReLU applied
  #pragma unroll
  for (int j = 0; j < 8; j++) {
    int i = t + 256 * j;
    int row = i >> 5, c4 = i & 31;
    int gr = r0 + row;
    float4 f = make_float4(0.f, 0.f, 0.f, 0.f);
    if (gr < N) f = *(const float4*)&x[(size_t)gr * 128 + c4 * 4];
    f.x = (f.x > 0.f) ? f.x : slope * f.x;
    f.y = (f.y > 0.f) ? f.y : slope * f.y;
    f.z = (f.z > 0.f) ? f.z : slope * f.z;
    f.w = (f.w > 0.f) ? f.w : slope * f.w;
    *(float4*)&sX[row][c4 * 4] = f;
  }
  __syncthreads();

  const int cg = t & 3, r = t >> 2;   // 4 col-groups x 64 rows
  const int c0 = cg * 16;
  float acc[16];
  #pragma unroll
  for (int j = 0; j < 16; j++) acc[j] = 0.f;

  for (int k = 0; k < 128; k++) {
    float a = sX[r][k];
    const float4* wp = (const float4*)&sW[k * 64 + c0];
    float4 w0 = wp[0], w1 = wp[1], w2 = wp[2], w3 = wp[3];
    acc[0]  = fmaf(a, w0.x, acc[0]);  acc[1]  = fmaf(a, w0.y, acc[1]);
    acc[2]  = fmaf(a, w0.z, acc[2]);  acc[3]  = fmaf(a, w0.w, acc[3]);
    acc[4]  = fmaf(a, w1.x, acc[4]);  acc[5]  = fmaf(a, w1.y, acc[5]);
    acc[6]  = fmaf(a, w1.z, acc[6]);  acc[7]  = fmaf(a, w1.w, acc[7]);
    acc[8]  = fmaf(a, w2.x, acc[8]);  acc[9]  = fmaf(a, w2.y, acc[9]);
    acc[10] = fmaf(a, w2.z, acc[10]); acc[11] = fmaf(a, w2.w, acc[11]);
    acc[12] = fmaf(a, w3.x, acc[12]); acc[13] = fmaf(a, w3.y, acc[13]);
    acc[14] = fmaf(a, w3.z, acc[14]); acc[15] = fmaf(a, w3.w, acc[15]);
  }

  int gr = r0 + r;
  if (gr < N) {
    // bf16 x_enc (for the edge gather)
    store16bf(&xenc[(size_t)gr * 128 + ch * 64 + c0], acc);
    // fp32 agg init with self-loop message
    #pragma unroll
    for (int q = 0; q < 4; q++) {
      float4 f;
      f.x = acc[4*q+0] + sLoop[c0 + 4*q + 0];
      f.y = acc[4*q+1] + sLoop[c0 + 4*q + 1];
      f.z = acc[4*q+2] + sLoop[c0 + 4*q + 2];
      f.w = acc[4*q+3] + sLoop[c0 + 4*q + 3];
      *(float4*)&agg[(size_t)gr * 128 + ch * 64 + c0 + 4*q] = f;
    }
  }
}

// =====================================================================
// Kernel 2: edge scatter. wave(64)-per-edge, 2 feats/lane, fp32 atomics.
// =====================================================================
__global__ __launch_bounds__(256) void k_scatter(
    const int* __restrict__ ei, const int* __restrict__ ea,
    const float* __restrict__ e1, const float* __restrict__ e2,
    const u16* __restrict__ xenc, float* __restrict__ agg, int E)
{
  int idx = blockIdx.x * 256 + threadIdx.x;
  int e = idx >> 6, lane = idx & 63;
  if (e >= E) return;
  int s  = ei[e];
  int d  = ei[E + e];
  int a1 = ea[2 * e];
  int a2 = ea[2 * e + 1];
  int c = lane * 2;
  u32    xv = *(const u32*)&xenc[(size_t)s * 128 + c];
  float2 w1 = *(const float2*)&e1[a1 * 128 + c];
  float2 w2 = *(const float2*)&e2[a2 * 128 + c];
  float m0 = bl(xv) + w1.x + w2.x;
  float m1 = bh(xv) + w1.y + w2.y;
  float* ap = &agg[(size_t)d * 128 + c];
  atomicAdd(ap,     m0);
  atomicAdd(ap + 1, m1);
}

// =====================================================================
// Kernel 3a: h = silu(agg @ W1 + b1)  -> bf16 [N,256]
// blockIdx.y = col-quarter (64 cols of 256). 64 rows/block.
// LDS: sW 32KB fp32 + sA 33.8KB fp32.
// =====================================================================
__global__ __launch_bounds__(256) void k_mlp1(
    const float* __restrict__ agg, const float* __restrict__ W1,
    const float* __restrict__ b1, u16* __restrict__ h, int N)
{
  __shared__ float sW[128 * 64];
  __shared__ float sA[64][132];

  const int t  = threadIdx.x;
  const int ch = blockIdx.y;          // 0..3 -> cols ch*64 .. +63
  #pragma unroll
  for (int j = 0; j < 8; j++) {
    int i = t + 256 * j;
    int row = i >> 4, c4 = i & 15;
    *(float4*)&sW[row * 64 + c4 * 4] =
        *(const float4*)&W1[row * 256 + ch * 64 + c4 * 4];
  }
  const int r0 = blockIdx.x * 64;
  #pragma unroll
  for (int j = 0; j < 8; j++) {
    int i = t + 256 * j;
    int row = i >> 5, c4 = i & 31;
    int gr = r0 + row;
    float4 f = make_float4(0.f, 0.f, 0.f, 0.f);
    if (gr < N) f = *(const float4*)&agg[(size_t)gr * 128 + c4 * 4];
    *(float4*)&sA[row][c4 * 4] = f;
  }
  __syncthreads();

  const int cg = t & 3, r = t >> 2;
  const int c0 = cg * 16;
  float acc[16];
  #pragma unroll
  for (int j = 0; j < 16; j++) acc[j] = 0.f;

  for (int k = 0; k < 128; k++) {
    float a = sA[r][k];
    const float4* wp = (const float4*)&sW[k * 64 + c0];
    float4 w0 = wp[0], w1 = wp[1], w2 = wp[2], w3 = wp[3];
    acc[0]  = fmaf(a, w0.x, acc[0]);  acc[1]  = fmaf(a, w0.y, acc[1]);
    acc[2]  = fmaf(a, w0.z, acc[2]);  acc[3]  = fmaf(a, w0.w, acc[3]);
    acc[4]  = fmaf(a, w1.x, acc[4]);  acc[5]  = fmaf(a, w1.y, acc[5]);
    acc[6]  = fmaf(a, w1.z, acc[6]);  acc[7]  = fmaf(a, w1.w, acc[7]);
    acc[8]  = fmaf(a, w2.x, acc[8]);  acc[9]  = fmaf(a, w2.y, acc[9]);
    acc[10] = fmaf(a, w2.z, acc[10]); acc[11] = fmaf(a, w2.w, acc[11]);
    acc[12] = fmaf(a, w3.x, acc[12]); acc[13] = fmaf(a, w3.y, acc[13]);
    acc[14] = fmaf(a, w3.z, acc[14]); acc[15] = fmaf(a, w3.w, acc[15]);
  }

  int gr = r0 + r;
  if (gr < N) {
    float v[16];
    #pragma unroll
    for (int j = 0; j < 16; j++) {
      float z = acc[j] + b1[ch * 64 + c0 + j];
      v[j] = z / (1.f + __expf(-z));          // silu
    }
    store16bf(&h[(size_t)gr * 256 + ch * 64 + c0], v);
  }
}

// =====================================================================
// Kernel 3b: out = h @ W2 + b2  -> fp32 [N,128]
// blockIdx.y = col-half (64 cols). 64 rows/block.
// LDS: sW bf16 32KB (converted on stage) + sA bf16 33.8KB.
// =====================================================================
__global__ __launch_bounds__(256) void k_mlp2(
    const u16* __restrict__ h, const float* __restrict__ W2,
    const float* __restrict__ b2, float* __restrict__ out, int N)
{
  __shared__ u16 sW[256 * 64];        // 32 KB
  __shared__ u16 sA[64 * 264];        // 33 KB, padded, rows 16B-aligned

  const int t  = threadIdx.x;
  const int ch = blockIdx.y;          // 0/1 -> cols ch*64 .. +63
  // stage W2 half, fp32 -> bf16: 256 rows x 64 cols; 8 elems/iter
  #pragma unroll
  for (int j = 0; j < 8; j++) {
    int i = t + 256 * j;
    int row = i >> 3, k8 = i & 7;
    const float4* src = (const float4*)&W2[row * 128 + ch * 64 + k8 * 8];
    float4 f0 = src[0], f1 = src[1];
    uint4 q;
    q.x = pk2(f0.x, f0.y); q.y = pk2(f0.z, f0.w);
    q.z = pk2(f1.x, f1.y); q.w = pk2(f1.z, f1.w);
    *(uint4*)&sW[row * 64 + k8 * 8] = q;
  }
  const int r0 = blockIdx.x * 64;
  // stage 64 h-rows (bf16): 32 chunks of 8 u16 per row
  #pragma unroll
  for (int j = 0; j < 8; j++) {
    int i = t + 256 * j;
    int row = i >> 5, chunk = i & 31;
    int gr = r0 + row;
    uint4 p = make_uint4(0u, 0u, 0u, 0u);
    if (gr < N) p = *(const uint4*)&h[(size_t)gr * 256 + chunk * 8];
    *(uint4*)&sA[row * 264 + chunk * 8] = p;
  }
  __syncthreads();

  const int cg = t & 3, r = t >> 2;   // 4 col-groups x 64 rows
  const int c0 = cg * 16;
  float acc[16];
  #pragma unroll
  for (int j = 0; j < 16; j++) acc[j] = 0.f;

  for (int k = 0; k < 256; k++) {
    float a = b2f(sA[r * 264 + k]);
    const uint4* wp = (const uint4*)&sW[k * 64 + c0];
    uint4 w0 = wp[0], w1 = wp[1];
    u32 u[8] = {w0.x, w0.y, w0.z, w0.w, w1.x, w1.y, w1.z, w1.w};
    #pragma unroll
    for (int j = 0; j < 8; j++) {
      acc[2*j]   = fmaf(a, bl(u[j]), acc[2*j]);
      acc[2*j+1] = fmaf(a, bh(u[j]), acc[2*j+1]);
    }
  }

  int gr = r0 + r;
  if (gr < N) {
    #pragma unroll
    for (int q = 0; q < 4; q++) {
      float4 f;
      f.x = acc[4*q+0] + b2[ch * 64 + c0 + 4*q + 0];
      f.y = acc[4*q+1] + b2[ch * 64 + c0 + 4*q + 1];
      f.z = acc[4*q+2] + b2[ch * 64 + c0 + 4*q + 2];
      f.w = acc[4*q+3] + b2[ch * 64 + c0 + 4*q + 3];
      *(float4*)&out[(size_t)gr * 128 + ch * 64 + c0 + 4*q] = f;
    }
  }
}

// =====================================================================
extern "C" void kernel_launch(void* const* d_in, const int* in_sizes, int n_in,
                              void* d_out, int out_size, void* d_ws, size_t ws_size,
                              hipStream_t stream) {
  const float* x    = (const float*)d_in[0];
  const int*   ei   = (const int*)d_in[1];
  const int*   ea   = (const int*)d_in[2];
  const float* pa   = (const float*)d_in[3];
  const float* Wenc = (const float*)d_in[4];
  const float* e1   = (const float*)d_in[5];
  const float* e2   = (const float*)d_in[6];
  const float* W1   = (const float*)d_in[7];
  const float* b1   = (const float*)d_in[8];
  const float* W2   = (const float*)d_in[9];
  const float* b2   = (const float*)d_in[10];
  float* out = (float*)d_out;

  const int N = in_sizes[0] / 128;
  const int E = in_sizes[1] / 2;

  char* ws = (char*)d_ws;
  u16*   xenc = (u16*)ws;                                         // N*128 bf16
  float* agg  = (float*)(ws + (size_t)N * 128 * 2);               // N*128 fp32
  u16*   hbuf = (u16*)(ws + (size_t)N * 128 * 2 + (size_t)N * 128 * 4); // N*256 bf16

  k_enc<<<dim3((N + 63) / 64, 2), 256, 0, stream>>>(x, pa, Wenc, e1, e2, xenc, agg, N);
  k_scatter<<<dim3((E * 64 + 255) / 256), 256, 0, stream>>>(ei, ea, e1, e2, xenc, agg, E);
  k_mlp1<<<dim3((N + 63) / 64, 4), 256, 0, stream>>>(agg, W1, b1, hbuf, N);
  k_mlp2<<<dim3((N + 63) / 64, 2), 256, 0, stream>>>(hbuf, W2, b2, out, N);
}

// Round 3
// 509.201 us; speedup vs baseline: 1.9434x; 1.9434x over previous
//
#include <hip/hip_runtime.h>

typedef unsigned short u16;
typedef unsigned int   u32;

// ---- bf16 helpers (bf16 = top 16 bits of fp32) ----
__device__ __forceinline__ float bl(u32 u){ union{u32 i; float f;} c; c.i = u << 16; return c.f; }
__device__ __forceinline__ float bh(u32 u){ union{u32 i; float f;} c; c.i = u & 0xffff0000u; return c.f; }
__device__ __forceinline__ u16 f2b(float f){
  union{float f; u32 i;} c; c.f = f;
  u32 i = c.i;
  u32 r = (i + 0x7fffu + ((i >> 16) & 1u)) >> 16;  // RNE
  return (u16)r;
}
__device__ __forceinline__ u32 pk2(float a, float b){
  return (u32)f2b(a) | ((u32)f2b(b) << 16);
}
__device__ __forceinline__ void store16bf(u16* dst, const float* v){
  uint4 q;
  q.x = pk2(v[0], v[1]);  q.y = pk2(v[2], v[3]);
  q.z = pk2(v[4], v[5]);  q.w = pk2(v[6], v[7]);
  ((uint4*)dst)[0] = q;
  q.x = pk2(v[8], v[9]);  q.y = pk2(v[10], v[11]);
  q.z = pk2(v[12], v[13]); q.w = pk2(v[14], v[15]);
  ((uint4*)dst)[1] = q;
}

// =====================================================================
// Kernel 1: x_enc = PReLU(x) @ W_enc    (fp32 in, bf16 out)
// blockIdx.y = col-half (64 cols). 64 rows/block, 256 thr.
// =====================================================================
__global__ __launch_bounds__(256) void k_enc(
    const float* __restrict__ x, const float* __restrict__ pa,
    const float* __restrict__ Wenc, u16* __restrict__ xenc, int N)
{
  __shared__ float sW[128 * 64];      // 32 KB  (col-half of W_enc)
  __shared__ float sX[64][132];       // 33.8 KB, padded

  const int t  = threadIdx.x;
  const int ch = blockIdx.y;
  #pragma unroll
  for (int j = 0; j < 8; j++) {
    int i = t + 256 * j;
    int row = i >> 4, c4 = i & 15;
    *(float4*)&sW[row * 64 + c4 * 4] =
        *(const float4*)&Wenc[row * 128 + ch * 64 + c4 * 4];
  }
  const float slope = pa[0];

  const int r0 = blockIdx.x * 64;
  #pragma unroll
  for (int j = 0; j < 8; j++) {
    int i = t + 256 * j;
    int row = i >> 5, c4 = i & 31;
    int gr = r0 + row;
    float4 f = make_float4(0.f, 0.f, 0.f, 0.f);
    if (gr < N) f = *(const float4*)&x[(size_t)gr * 128 + c4 * 4];
    f.x = (f.x > 0.f) ? f.x : slope * f.x;
    f.y = (f.y > 0.f) ? f.y : slope * f.y;
    f.z = (f.z > 0.f) ? f.z : slope * f.z;
    f.w = (f.w > 0.f) ? f.w : slope * f.w;
    *(float4*)&sX[row][c4 * 4] = f;
  }
  __syncthreads();

  const int cg = t & 3, r = t >> 2;   // 4 col-groups x 64 rows
  const int c0 = cg * 16;
  float acc[16];
  #pragma unroll
  for (int j = 0; j < 16; j++) acc[j] = 0.f;

  for (int k = 0; k < 128; k++) {
    float a = sX[r][k];
    const float4* wp = (const float4*)&sW[k * 64 + c0];
    float4 w0 = wp[0], w1 = wp[1], w2 = wp[2], w3 = wp[3];
    acc[0]  = fmaf(a, w0.x, acc[0]);  acc[1]  = fmaf(a, w0.y, acc[1]);
    acc[2]  = fmaf(a, w0.z, acc[2]);  acc[3]  = fmaf(a, w0.w, acc[3]);
    acc[4]  = fmaf(a, w1.x, acc[4]);  acc[5]  = fmaf(a, w1.y, acc[5]);
    acc[6]  = fmaf(a, w1.z, acc[6]);  acc[7]  = fmaf(a, w1.w, acc[7]);
    acc[8]  = fmaf(a, w2.x, acc[8]);  acc[9]  = fmaf(a, w2.y, acc[9]);
    acc[10] = fmaf(a, w2.z, acc[10]); acc[11] = fmaf(a, w2.w, acc[11]);
    acc[12] = fmaf(a, w3.x, acc[12]); acc[13] = fmaf(a, w3.y, acc[13]);
    acc[14] = fmaf(a, w3.z, acc[14]); acc[15] = fmaf(a, w3.w, acc[15]);
  }

  int gr = r0 + r;
  if (gr < N) store16bf(&xenc[(size_t)gr * 128 + ch * 64 + c0], acc);
}

// =====================================================================
// CSR build: count -> scan (3 kernels) -> fill packed records
// rec = src | (a1*6+a2) << 26     (N < 2^26, a1,a2 < 6)
// =====================================================================
__global__ __launch_bounds__(256) void k_count(
    const int* __restrict__ ei, int* __restrict__ cnt, int E)
{
  int e = blockIdx.x * 256 + threadIdx.x;
  if (e < E) atomicAdd(&cnt[ei[E + e]], 1);
}

__global__ __launch_bounds__(256) void k_scan_block(
    const int* __restrict__ cnt, int* __restrict__ offs,
    int* __restrict__ bsum, int n)
{
  __shared__ int sS[256];
  const int b = blockIdx.x, t = threadIdx.x;
  const int i0 = b * 1024 + t * 4;
  int4 v = make_int4(0, 0, 0, 0);
  if (i0 + 3 < n) v = *(const int4*)&cnt[i0];
  else {
    if (i0     < n) v.x = cnt[i0];
    if (i0 + 1 < n) v.y = cnt[i0 + 1];
    if (i0 + 2 < n) v.z = cnt[i0 + 2];
  }
  int s = v.x + v.y + v.z + v.w;
  sS[t] = s;
  __syncthreads();
  for (int d = 1; d < 256; d <<= 1) {
    int val = (t >= d) ? sS[t - d] : 0;
    __syncthreads();
    sS[t] += val;
    __syncthreads();
  }
  int ex = sS[t] - s;              // exclusive within block
  if (t == 255) bsum[b] = sS[t];   // block total
  int o0 = ex, o1 = o0 + v.x, o2 = o1 + v.y, o3 = o2 + v.z;
  if (i0     < n) offs[i0]     = o0;
  if (i0 + 1 < n) offs[i0 + 1] = o1;
  if (i0 + 2 < n) offs[i0 + 2] = o2;
  if (i0 + 3 < n) offs[i0 + 3] = o3;
}

__global__ void k_scan_bsum(int* __restrict__ bsum, int nb)
{
  if (threadIdx.x == 0 && blockIdx.x == 0) {
    int acc = 0;
    for (int i = 0; i < nb; i++) { int t = bsum[i]; bsum[i] = acc; acc += t; }
  }
}

__global__ __launch_bounds__(256) void k_scan_add(
    int* __restrict__ offs, int* __restrict__ cursor,
    const int* __restrict__ bsum, int n, int E)
{
  int i = blockIdx.x * 256 + threadIdx.x;
  if (i < n) {
    int v = offs[i] + bsum[i >> 10];
    offs[i] = v;
    cursor[i] = v;
  }
  if (i == n) offs[n] = E;
}

__global__ __launch_bounds__(256) void k_fill(
    const int* __restrict__ ei, const int* __restrict__ ea,
    int* __restrict__ cursor, u32* __restrict__ recs, int E)
{
  int e = blockIdx.x * 256 + threadIdx.x;
  if (e >= E) return;
  int src = ei[e];
  int dst = ei[E + e];
  int2 a = *(const int2*)&ea[2 * e];
  int pos = atomicAdd(&cursor[dst], 1);
  recs[pos] = (u32)src | ((u32)(a.x * 6 + a.y) << 26);
}

// =====================================================================
// Gather: one wave per node, 2 feats/lane. agg written once, coalesced.
// 36 precombined edge embeddings (e1[a]+e2[b]) staged in LDS.
// =====================================================================
__global__ __launch_bounds__(256) void k_gather(
    const int* __restrict__ offs, const u32* __restrict__ recs,
    const float* __restrict__ e1, const float* __restrict__ e2,
    const u32* __restrict__ xenc32, float* __restrict__ agg, int N)
{
  __shared__ float2 sE[36 * 64];   // 18.4 KB: combo-major, lane-minor

  const int t = threadIdx.x;
  for (int i = t; i < 36 * 64; i += 256) {
    int comb = i >> 6, l = i & 63;
    int c1 = comb / 6, c2 = comb - c1 * 6;
    float2 v1 = *(const float2*)&e1[c1 * 128 + 2 * l];
    float2 v2 = *(const float2*)&e2[c2 * 128 + 2 * l];
    sE[i] = make_float2(v1.x + v2.x, v1.y + v2.y);
  }
  __syncthreads();

  const int v = blockIdx.x * 4 + (t >> 6);
  if (v >= N) return;
  const int lane = t & 63;

  // self-loop init: comb = 5*6+0 = 30
  u32 xv = xenc32[(size_t)v * 64 + lane];
  float2 ec = sE[30 * 64 + lane];
  float a0 = bl(xv) + ec.x;
  float a1 = bh(xv) + ec.y;

  const int beg = offs[v], end = offs[v + 1];
  for (int j = beg; j < end; j += 64) {
    u32 rv = 0;
    if (j + lane < end) rv = recs[j + lane];
    int cnt = min(64, end - j);
    for (int jj = 0; jj < cnt; jj++) {
      u32 r = __shfl(rv, jj);
      int src = r & 0x3ffffff;
      int comb = r >> 26;
      u32 x2 = xenc32[(size_t)src * 64 + lane];
      float2 e = sE[comb * 64 + lane];
      a0 += bl(x2) + e.x;
      a1 += bh(x2) + e.y;
    }
  }
  *(float2*)&agg[(size_t)v * 128 + 2 * lane] = make_float2(a0, a1);
}

// =====================================================================
// Kernel 3a: h = silu(agg @ W1 + b1)  -> bf16 [N,256]
// =====================================================================
__global__ __launch_bounds__(256) void k_mlp1(
    const float* __restrict__ agg, const float* __restrict__ W1,
    const float* __restrict__ b1, u16* __restrict__ h, int N)
{
  __shared__ float sW[128 * 64];
  __shared__ float sA[64][132];

  const int t  = threadIdx.x;
  const int ch = blockIdx.y;          // 0..3
  #pragma unroll
  for (int j = 0; j < 8; j++) {
    int i = t + 256 * j;
    int row = i >> 4, c4 = i & 15;
    *(float4*)&sW[row * 64 + c4 * 4] =
        *(const float4*)&W1[row * 256 + ch * 64 + c4 * 4];
  }
  const int r0 = blockIdx.x * 64;
  #pragma unroll
  for (int j = 0; j < 8; j++) {
    int i = t + 256 * j;
    int row = i >> 5, c4 = i & 31;
    int gr = r0 + row;
    float4 f = make_float4(0.f, 0.f, 0.f, 0.f);
    if (gr < N) f = *(const float4*)&agg[(size_t)gr * 128 + c4 * 4];
    *(float4*)&sA[row][c4 * 4] = f;
  }
  __syncthreads();

  const int cg = t & 3, r = t >> 2;
  const int c0 = cg * 16;
  float acc[16];
  #pragma unroll
  for (int j = 0; j < 16; j++) acc[j] = 0.f;

  for (int k = 0; k < 128; k++) {
    float a = sA[r][k];
    const float4* wp = (const float4*)&sW[k * 64 + c0];
    float4 w0 = wp[0], w1 = wp[1], w2 = wp[2], w3 = wp[3];
    acc[0]  = fmaf(a, w0.x, acc[0]);  acc[1]  = fmaf(a, w0.y, acc[1]);
    acc[2]  = fmaf(a, w0.z, acc[2]);  acc[3]  = fmaf(a, w0.w, acc[3]);
    acc[4]  = fmaf(a, w1.x, acc[4]);  acc[5]  = fmaf(a, w1.y, acc[5]);
    acc[6]  = fmaf(a, w1.z, acc[6]);  acc[7]  = fmaf(a, w1.w, acc[7]);
    acc[8]  = fmaf(a, w2.x, acc[8]);  acc[9]  = fmaf(a, w2.y, acc[9]);
    acc[10] = fmaf(a, w2.z, acc[10]); acc[11] = fmaf(a, w2.w, acc[11]);
    acc[12] = fmaf(a, w3.x, acc[12]); acc[13] = fmaf(a, w3.y, acc[13]);
    acc[14] = fmaf(a, w3.z, acc[14]); acc[15] = fmaf(a, w3.w, acc[15]);
  }

  int gr = r0 + r;
  if (gr < N) {
    float v[16];
    #pragma unroll
    for (int j = 0; j < 16; j++) {
      float z = acc[j] + b1[ch * 64 + c0 + j];
      v[j] = z / (1.f + __expf(-z));          // silu
    }
    store16bf(&h[(size_t)gr * 256 + ch * 64 + c0], v);
  }
}

// =====================================================================
// Kernel 3b: out = h @ W2 + b2  -> fp32 [N,128]
// =====================================================================
__global__ __launch_bounds__(256) void k_mlp2(
    const u16* __restrict__ h, const float* __restrict__ W2,
    const float* __restrict__ b2, float* __restrict__ out, int N)
{
  __shared__ u16 sW[256 * 64];        // 32 KB
  __shared__ u16 sA[64 * 264];        // 33 KB

  const int t  = threadIdx.x;
  const int ch = blockIdx.y;
  #pragma unroll
  for (int j = 0; j < 8; j++) {
    int i = t + 256 * j;
    int row = i >> 3, k8 = i & 7;
    const float4* src = (const float4*)&W2[row * 128 + ch * 64 + k8 * 8];
    float4 f0 = src[0], f1 = src[1];
    uint4 q;
    q.x = pk2(f0.x, f0.y); q.y = pk2(f0.z, f0.w);
    q.z = pk2(f1.x, f1.y); q.w = pk2(f1.z, f1.w);
    *(uint4*)&sW[row * 64 + k8 * 8] = q;
  }
  const int r0 = blockIdx.x * 64;
  #pragma unroll
  for (int j = 0; j < 8; j++) {
    int i = t + 256 * j;
    int row = i >> 5, chunk = i & 31;
    int gr = r0 + row;
    uint4 p = make_uint4(0u, 0u, 0u, 0u);
    if (gr < N) p = *(const uint4*)&h[(size_t)gr * 256 + chunk * 8];
    *(uint4*)&sA[row * 264 + chunk * 8] = p;
  }
  __syncthreads();

  const int cg = t & 3, r = t >> 2;
  const int c0 = cg * 16;
  float acc[16];
  #pragma unroll
  for (int j = 0; j < 16; j++) acc[j] = 0.f;

  for (int k = 0; k < 256; k++) {
    float a = bl(((u32)sA[r * 264 + k]) << 16 >> 16 ? 0u : 0u) ; // placeholder removed below
    (void)a;
    break;
  }
  // (re-written clean loop)
  #pragma unroll
  for (int j = 0; j < 16; j++) acc[j] = 0.f;
  for (int k = 0; k < 256; k++) {
    union { u32 i; float f; } cv; cv.i = ((u32)sA[r * 264 + k]) << 16;
    float a = cv.f;
    const uint4* wp = (const uint4*)&sW[k * 64 + c0];
    uint4 w0 = wp[0], w1 = wp[1];
    u32 u[8] = {w0.x, w0.y, w0.z, w0.w, w1.x, w1.y, w1.z, w1.w};
    #pragma unroll
    for (int j = 0; j < 8; j++) {
      acc[2*j]   = fmaf(a, bl(u[j]), acc[2*j]);
      acc[2*j+1] = fmaf(a, bh(u[j]), acc[2*j+1]);
    }
  }

  int gr = r0 + r;
  if (gr < N) {
    #pragma unroll
    for (int q = 0; q < 4; q++) {
      float4 f;
      f.x = acc[4*q+0] + b2[ch * 64 + c0 + 4*q + 0];
      f.y = acc[4*q+1] + b2[ch * 64 + c0 + 4*q + 1];
      f.z = acc[4*q+2] + b2[ch * 64 + c0 + 4*q + 2];
      f.w = acc[4*q+3] + b2[ch * 64 + c0 + 4*q + 3];
      *(float4*)&out[(size_t)gr * 128 + ch * 64 + c0 + 4*q] = f;
    }
  }
}

// =====================================================================
extern "C" void kernel_launch(void* const* d_in, const int* in_sizes, int n_in,
                              void* d_out, int out_size, void* d_ws, size_t ws_size,
                              hipStream_t stream) {
  const float* x    = (const float*)d_in[0];
  const int*   ei   = (const int*)d_in[1];
  const int*   ea   = (const int*)d_in[2];
  const float* pa   = (const float*)d_in[3];
  const float* Wenc = (const float*)d_in[4];
  const float* e1   = (const float*)d_in[5];
  const float* e2   = (const float*)d_in[6];
  const float* W1   = (const float*)d_in[7];
  const float* b1   = (const float*)d_in[8];
  const float* W2   = (const float*)d_in[9];
  const float* b2   = (const float*)d_in[10];
  float* out = (float*)d_out;

  const int N = in_sizes[0] / 128;
  const int E = in_sizes[1] / 2;

  char* ws = (char*)d_ws;
  size_t off = 0;
  auto alloc = [&](size_t bytes) {
    void* p = ws + off;
    off = (off + bytes + 255) & ~(size_t)255;
    return p;
  };
  u16*   xenc   = (u16*)  alloc((size_t)N * 128 * 2);
  float* agg    = (float*)alloc((size_t)N * 128 * 4);
  u16*   hbuf   = (u16*)  alloc((size_t)N * 256 * 2);
  int*   cnt    = (int*)  alloc((size_t)N * 4);
  int*   offs   = (int*)  alloc((size_t)(N + 1) * 4);
  int*   cursor = (int*)  alloc((size_t)N * 4);
  int*   bsum   = (int*)  alloc(256 * 4);
  u32*   recs   = (u32*)  alloc((size_t)E * 4);

  const int nb = (N + 1023) / 1024;

  hipMemsetAsync(cnt, 0, (size_t)N * 4, stream);
  k_enc<<<dim3((N + 63) / 64, 2), 256, 0, stream>>>(x, pa, Wenc, xenc, N);
  k_count<<<(E + 255) / 256, 256, 0, stream>>>(ei, cnt, E);
  k_scan_block<<<nb, 256, 0, stream>>>(cnt, offs, bsum, N);
  k_scan_bsum<<<1, 64, 0, stream>>>(bsum, nb);
  k_scan_add<<<(N + 256) / 256, 256, 0, stream>>>(offs, cursor, bsum, N, E);
  k_fill<<<(E + 255) / 256, 256, 0, stream>>>(ei, ea, cursor, recs, E);
  k_gather<<<(N + 3) / 4, 256, 0, stream>>>(offs, recs, e1, e2, (const u32*)xenc, agg, N);
  k_mlp1<<<dim3((N + 63) / 64, 4), 256, 0, stream>>>(agg, W1, b1, hbuf, N);
  k_mlp2<<<dim3((N + 63) / 64, 2), 256, 0, stream>>>(hbuf, W2, b2, out, N);
}

// Round 4
// 315.041 us; speedup vs baseline: 3.1411x; 1.6163x over previous
//
#include <hip/hip_runtime.h>

typedef unsigned short u16;
typedef unsigned int   u32;
typedef __attribute__((ext_vector_type(8))) short short8;   // 8 bf16 (4 VGPRs)
typedef __attribute__((ext_vector_type(4))) float f32x4;    // MFMA C/D

// ---- bf16 helpers (bf16 = top 16 bits of fp32; half-up rounding) ----
__device__ __forceinline__ float bl(u32 u){ union{u32 i; float f;} c; c.i = u << 16; return c.f; }
__device__ __forceinline__ float bh(u32 u){ union{u32 i; float f;} c; c.i = u & 0xffff0000u; return c.f; }
__device__ __forceinline__ u16 f2b(float f){
  union{float f; u32 i;} c; c.f = f;
  return (u16)((c.i + 0x8000u) >> 16);
}
__device__ __forceinline__ u32 pk2(float a, float b){
  union{float f; u32 i;} x, y; x.f = a; y.f = b;
  return ((x.i + 0x8000u) >> 16) | ((y.i + 0x8000u) & 0xffff0000u);
}

// =====================================================================
// k_prep: transpose weights to bf16 n-major  WT[n][k]
//   WencT [128][128], W1T [256][128], W2T [128][256]
// =====================================================================
__global__ __launch_bounds__(256) void k_prep(
    const float* __restrict__ Wenc, const float* __restrict__ W1,
    const float* __restrict__ W2, u16* __restrict__ WencT,
    u16* __restrict__ W1T, u16* __restrict__ W2T)
{
  int i = blockIdx.x * 256 + threadIdx.x;
  if (i < 16384) {                       // WencT: n=i>>7, k=i&127
    int n = i >> 7, k = i & 127;
    WencT[i] = f2b(Wenc[k * 128 + n]);
  } else if (i < 16384 + 32768) {        // W1T: [256 n][128 k]
    int j = i - 16384;
    int n = j >> 7, k = j & 127;
    W1T[j] = f2b(W1[k * 256 + n]);
  } else if (i < 16384 + 32768 + 32768) { // W2T: [128 n][256 k]
    int j = i - 49152;
    int n = j >> 8, k = j & 255;
    W2T[j] = f2b(W2[k * 128 + n]);
  }
}

// =====================================================================
// k_enc: xenc = bf16( PReLU(x) @ W_enc )    [N,128]
// MFMA 16x16x32 bf16. Wave: 32 rows x 128 cols. Block: 4 waves = 128 rows.
// =====================================================================
__global__ __launch_bounds__(256) void k_enc(
    const float* __restrict__ x, const float* __restrict__ pa,
    const u16* __restrict__ WT, u16* __restrict__ xenc, int N)
{
  const int K = 128, SK = 136, NT = 8;
  __shared__ u16 sB[128 * SK];           // 34 KB

  const int t = threadIdx.x;
  #pragma unroll
  for (int j = 0; j < 8; j++) {          // 2048 16B chunks
    int i = t + 256 * j;
    int n = i >> 4, k8 = i & 15;
    *(uint4*)&sB[n * SK + k8 * 8] = *(const uint4*)&WT[n * K + k8 * 8];
  }
  __syncthreads();

  const float slope = pa[0];
  const int lane = t & 63, wave = t >> 6, quad = lane >> 4, l16 = lane & 15;
  const int m0 = blockIdx.x * 128 + wave * 32;
  if (m0 >= N) return;

  f32x4 acc[2][NT];
  #pragma unroll
  for (int mr = 0; mr < 2; mr++)
    #pragma unroll
    for (int nt = 0; nt < NT; nt++) acc[mr][nt] = (f32x4){0.f, 0.f, 0.f, 0.f};

  #pragma unroll
  for (int ks = 0; ks < 4; ks++) {
    const int k0 = ks * 32 + quad * 8;
    union { u32 u[4]; short8 s; } a[2];
    #pragma unroll
    for (int mr = 0; mr < 2; mr++) {
      int row = m0 + mr * 16 + l16; row = min(row, N - 1);
      const float4* ap = (const float4*)&x[(size_t)row * 128 + k0];
      float4 f0 = ap[0], f1 = ap[1];
      float v0 = f0.x > 0.f ? f0.x : slope * f0.x;
      float v1 = f0.y > 0.f ? f0.y : slope * f0.y;
      float v2 = f0.z > 0.f ? f0.z : slope * f0.z;
      float v3 = f0.w > 0.f ? f0.w : slope * f0.w;
      float v4 = f1.x > 0.f ? f1.x : slope * f1.x;
      float v5 = f1.y > 0.f ? f1.y : slope * f1.y;
      float v6 = f1.z > 0.f ? f1.z : slope * f1.z;
      float v7 = f1.w > 0.f ? f1.w : slope * f1.w;
      a[mr].u[0] = pk2(v0, v1); a[mr].u[1] = pk2(v2, v3);
      a[mr].u[2] = pk2(v4, v5); a[mr].u[3] = pk2(v6, v7);
    }
    #pragma unroll
    for (int nt = 0; nt < NT; nt++) {
      short8 b = *(const short8*)&sB[(nt * 16 + l16) * SK + k0];
      acc[0][nt] = __builtin_amdgcn_mfma_f32_16x16x32_bf16(a[0].s, b, acc[0][nt], 0, 0, 0);
      acc[1][nt] = __builtin_amdgcn_mfma_f32_16x16x32_bf16(a[1].s, b, acc[1][nt], 0, 0, 0);
    }
  }

  #pragma unroll
  for (int mr = 0; mr < 2; mr++)
    #pragma unroll
    for (int nt = 0; nt < NT; nt++) {
      int col = nt * 16 + l16;
      #pragma unroll
      for (int r = 0; r < 4; r++) {
        int row = m0 + mr * 16 + quad * 4 + r;
        if (row < N) xenc[(size_t)row * 128 + col] = f2b(acc[mr][nt][r]);
      }
    }
}

// =====================================================================
// CSR build: count -> scan -> fill packed records
// rec = src | (a1*6+a2) << 26
// =====================================================================
__global__ __launch_bounds__(256) void k_count(
    const int* __restrict__ ei, int* __restrict__ cnt, int E)
{
  int e = blockIdx.x * 256 + threadIdx.x;
  if (e < E) atomicAdd(&cnt[ei[E + e]], 1);
}

__global__ __launch_bounds__(256) void k_scan_block(
    const int* __restrict__ cnt, int* __restrict__ offs,
    int* __restrict__ bsum, int n)
{
  __shared__ int sS[256];
  const int b = blockIdx.x, t = threadIdx.x;
  const int i0 = b * 1024 + t * 4;
  int4 v = make_int4(0, 0, 0, 0);
  if (i0 + 3 < n) v = *(const int4*)&cnt[i0];
  else {
    if (i0     < n) v.x = cnt[i0];
    if (i0 + 1 < n) v.y = cnt[i0 + 1];
    if (i0 + 2 < n) v.z = cnt[i0 + 2];
  }
  int s = v.x + v.y + v.z + v.w;
  sS[t] = s;
  __syncthreads();
  for (int d = 1; d < 256; d <<= 1) {
    int val = (t >= d) ? sS[t - d] : 0;
    __syncthreads();
    sS[t] += val;
    __syncthreads();
  }
  int ex = sS[t] - s;
  if (t == 255) bsum[b] = sS[t];
  int o0 = ex, o1 = o0 + v.x, o2 = o1 + v.y, o3 = o2 + v.z;
  if (i0     < n) offs[i0]     = o0;
  if (i0 + 1 < n) offs[i0 + 1] = o1;
  if (i0 + 2 < n) offs[i0 + 2] = o2;
  if (i0 + 3 < n) offs[i0 + 3] = o3;
}

__global__ void k_scan_bsum(int* __restrict__ bsum, int nb)
{
  if (threadIdx.x == 0 && blockIdx.x == 0) {
    int acc = 0;
    for (int i = 0; i < nb; i++) { int t = bsum[i]; bsum[i] = acc; acc += t; }
  }
}

__global__ __launch_bounds__(256) void k_scan_add(
    int* __restrict__ offs, int* __restrict__ cursor,
    const int* __restrict__ bsum, int n, int E)
{
  int i = blockIdx.x * 256 + threadIdx.x;
  if (i < n) {
    int v = offs[i] + bsum[i >> 10];
    offs[i] = v;
    cursor[i] = v;
  }
  if (i == n) offs[n] = E;
}

__global__ __launch_bounds__(256) void k_fill(
    const int* __restrict__ ei, const int* __restrict__ ea,
    int* __restrict__ cursor, u32* __restrict__ recs, int E)
{
  int e = blockIdx.x * 256 + threadIdx.x;
  if (e >= E) return;
  int src = ei[e];
  int dst = ei[E + e];
  int2 a = *(const int2*)&ea[2 * e];
  int pos = atomicAdd(&cursor[dst], 1);
  recs[pos] = (u32)src | ((u32)(a.x * 6 + a.y) << 26);
}

// =====================================================================
// Gather: one wave per node, 2 feats/lane. agg written once, coalesced.
// =====================================================================
__global__ __launch_bounds__(256) void k_gather(
    const int* __restrict__ offs, const u32* __restrict__ recs,
    const float* __restrict__ e1, const float* __restrict__ e2,
    const u32* __restrict__ xenc32, float* __restrict__ agg, int N)
{
  __shared__ float2 sE[36 * 64];   // 18.4 KB

  const int t = threadIdx.x;
  for (int i = t; i < 36 * 64; i += 256) {
    int comb = i >> 6, l = i & 63;
    int c1 = comb / 6, c2 = comb - c1 * 6;
    float2 v1 = *(const float2*)&e1[c1 * 128 + 2 * l];
    float2 v2 = *(const float2*)&e2[c2 * 128 + 2 * l];
    sE[i] = make_float2(v1.x + v2.x, v1.y + v2.y);
  }
  __syncthreads();

  const int v = blockIdx.x * 4 + (t >> 6);
  if (v >= N) return;
  const int lane = t & 63;

  u32 xv = xenc32[(size_t)v * 64 + lane];
  float2 ec = sE[30 * 64 + lane];      // self-loop combo 5*6+0
  float a0 = bl(xv) + ec.x;
  float a1 = bh(xv) + ec.y;

  const int beg = offs[v], end = offs[v + 1];
  for (int j = beg; j < end; j += 64) {
    u32 rv = 0;
    if (j + lane < end) rv = recs[j + lane];
    int cnt = min(64, end - j);
    for (int jj = 0; jj < cnt; jj++) {
      u32 r = __shfl(rv, jj);
      int src = r & 0x3ffffff;
      int comb = r >> 26;
      u32 x2 = xenc32[(size_t)src * 64 + lane];
      float2 e = sE[comb * 64 + lane];
      a0 += bl(x2) + e.x;
      a1 += bh(x2) + e.y;
    }
  }
  *(float2*)&agg[(size_t)v * 128 + 2 * lane] = make_float2(a0, a1);
}

// =====================================================================
// k_mlp1: h = bf16( silu(agg @ W1 + b1) )   [N,256]
// =====================================================================
__global__ __launch_bounds__(256) void k_mlp1(
    const float* __restrict__ agg, const u16* __restrict__ WT,
    const float* __restrict__ b1, u16* __restrict__ h, int N)
{
  const int K = 128, SK = 136, NT = 16;
  __shared__ u16   sB[256 * SK];       // 68 KB
  __shared__ float sBias[256];

  const int t = threadIdx.x;
  #pragma unroll
  for (int j = 0; j < 16; j++) {       // 4096 16B chunks
    int i = t + 256 * j;
    int n = i >> 4, k8 = i & 15;
    *(uint4*)&sB[n * SK + k8 * 8] = *(const uint4*)&WT[n * K + k8 * 8];
  }
  if (t < 256) sBias[t] = b1[t];
  __syncthreads();

  const int lane = t & 63, wave = t >> 6, quad = lane >> 4, l16 = lane & 15;
  const int m0 = blockIdx.x * 128 + wave * 32;
  if (m0 >= N) return;

  f32x4 acc[2][NT];
  #pragma unroll
  for (int mr = 0; mr < 2; mr++)
    #pragma unroll
    for (int nt = 0; nt < NT; nt++) acc[mr][nt] = (f32x4){0.f, 0.f, 0.f, 0.f};

  #pragma unroll
  for (int ks = 0; ks < 4; ks++) {
    const int k0 = ks * 32 + quad * 8;
    union { u32 u[4]; short8 s; } a[2];
    #pragma unroll
    for (int mr = 0; mr < 2; mr++) {
      int row = m0 + mr * 16 + l16; row = min(row, N - 1);
      const float4* ap = (const float4*)&agg[(size_t)row * 128 + k0];
      float4 f0 = ap[0], f1 = ap[1];
      a[mr].u[0] = pk2(f0.x, f0.y); a[mr].u[1] = pk2(f0.z, f0.w);
      a[mr].u[2] = pk2(f1.x, f1.y); a[mr].u[3] = pk2(f1.z, f1.w);
    }
    #pragma unroll
    for (int nt = 0; nt < NT; nt++) {
      short8 b = *(const short8*)&sB[(nt * 16 + l16) * SK + k0];
      acc[0][nt] = __builtin_amdgcn_mfma_f32_16x16x32_bf16(a[0].s, b, acc[0][nt], 0, 0, 0);
      acc[1][nt] = __builtin_amdgcn_mfma_f32_16x16x32_bf16(a[1].s, b, acc[1][nt], 0, 0, 0);
    }
  }

  #pragma unroll
  for (int mr = 0; mr < 2; mr++)
    #pragma unroll
    for (int nt = 0; nt < NT; nt++) {
      int col = nt * 16 + l16;
      float bias = sBias[col];
      #pragma unroll
      for (int r = 0; r < 4; r++) {
        int row = m0 + mr * 16 + quad * 4 + r;
        if (row < N) {
          float z = acc[mr][nt][r] + bias;
          float s = z / (1.f + __expf(-z));
          h[(size_t)row * 256 + col] = f2b(s);
        }
      }
    }
}

// =====================================================================
// k_mlp2: out = h @ W2 + b2   [N,128] fp32
// =====================================================================
__global__ __launch_bounds__(256) void k_mlp2(
    const u16* __restrict__ h, const u16* __restrict__ WT,
    const float* __restrict__ b2, float* __restrict__ out, int N)
{
  const int K = 256, SK = 264, NT = 8;
  __shared__ u16   sB[128 * SK];       // 66 KB
  __shared__ float sBias[128];

  const int t = threadIdx.x;
  #pragma unroll
  for (int j = 0; j < 16; j++) {       // 4096 16B chunks
    int i = t + 256 * j;
    int n = i >> 5, k8 = i & 31;
    *(uint4*)&sB[n * SK + k8 * 8] = *(const uint4*)&WT[n * K + k8 * 8];
  }
  if (t < 128) sBias[t] = b2[t];
  __syncthreads();

  const int lane = t & 63, wave = t >> 6, quad = lane >> 4, l16 = lane & 15;
  const int m0 = blockIdx.x * 128 + wave * 32;
  if (m0 >= N) return;

  f32x4 acc[2][NT];
  #pragma unroll
  for (int mr = 0; mr < 2; mr++)
    #pragma unroll
    for (int nt = 0; nt < NT; nt++) acc[mr][nt] = (f32x4){0.f, 0.f, 0.f, 0.f};

  #pragma unroll
  for (int ks = 0; ks < 8; ks++) {
    const int k0 = ks * 32 + quad * 8;
    union { uint4 q; short8 s; } a[2];
    #pragma unroll
    for (int mr = 0; mr < 2; mr++) {
      int row = m0 + mr * 16 + l16; row = min(row, N - 1);
      a[mr].q = *(const uint4*)&h[(size_t)row * 256 + k0];
    }
    #pragma unroll
    for (int nt = 0; nt < NT; nt++) {
      short8 b = *(const short8*)&sB[(nt * 16 + l16) * SK + k0];
      acc[0][nt] = __builtin_amdgcn_mfma_f32_16x16x32_bf16(a[0].s, b, acc[0][nt], 0, 0, 0);
      acc[1][nt] = __builtin_amdgcn_mfma_f32_16x16x32_bf16(a[1].s, b, acc[1][nt], 0, 0, 0);
    }
  }

  #pragma unroll
  for (int mr = 0; mr < 2; mr++)
    #pragma unroll
    for (int nt = 0; nt < NT; nt++) {
      int col = nt * 16 + l16;
      float bias = sBias[col];
      #pragma unroll
      for (int r = 0; r < 4; r++) {
        int row = m0 + mr * 16 + quad * 4 + r;
        if (row < N) out[(size_t)row * 128 + col] = acc[mr][nt][r] + bias;
      }
    }
}

// =====================================================================
extern "C" void kernel_launch(void* const* d_in, const int* in_sizes, int n_in,
                              void* d_out, int out_size, void* d_ws, size_t ws_size,
                              hipStream_t stream) {
  const float* x    = (const float*)d_in[0];
  const int*   ei   = (const int*)d_in[1];
  const int*   ea   = (const int*)d_in[2];
  const float* pa   = (const float*)d_in[3];
  const float* Wenc = (const float*)d_in[4];
  const float* e1   = (const float*)d_in[5];
  const float* e2   = (const float*)d_in[6];
  const float* W1   = (const float*)d_in[7];
  const float* b1   = (const float*)d_in[8];
  const float* W2   = (const float*)d_in[9];
  const float* b2   = (const float*)d_in[10];
  float* out = (float*)d_out;

  const int N = in_sizes[0] / 128;
  const int E = in_sizes[1] / 2;

  char* ws = (char*)d_ws;
  size_t off = 0;
  auto alloc = [&](size_t bytes) {
    void* p = ws + off;
    off = (off + bytes + 255) & ~(size_t)255;
    return p;
  };
  u16*   xenc   = (u16*)  alloc((size_t)N * 128 * 2);
  float* agg    = (float*)alloc((size_t)N * 128 * 4);
  u16*   hbuf   = (u16*)  alloc((size_t)N * 256 * 2);
  int*   cnt    = (int*)  alloc((size_t)N * 4);
  int*   offs   = (int*)  alloc((size_t)(N + 1) * 4);
  int*   cursor = (int*)  alloc((size_t)N * 4);
  int*   bsum   = (int*)  alloc(256 * 4);
  u32*   recs   = (u32*)  alloc((size_t)E * 4);
  u16*   WencT  = (u16*)  alloc(128 * 128 * 2);
  u16*   W1T    = (u16*)  alloc(256 * 128 * 2);
  u16*   W2T    = (u16*)  alloc(128 * 256 * 2);

  const int nb = (N + 1023) / 1024;
  const int gemm_blocks = (N + 127) / 128;

  hipMemsetAsync(cnt, 0, (size_t)N * 4, stream);
  k_prep<<<320, 256, 0, stream>>>(Wenc, W1, W2, WencT, W1T, W2T);
  k_enc<<<gemm_blocks, 256, 0, stream>>>(x, pa, WencT, xenc, N);
  k_count<<<(E + 255) / 256, 256, 0, stream>>>(ei, cnt, E);
  k_scan_block<<<nb, 256, 0, stream>>>(cnt, offs, bsum, N);
  k_scan_bsum<<<1, 64, 0, stream>>>(bsum, nb);
  k_scan_add<<<(N + 256) / 256, 256, 0, stream>>>(offs, cursor, bsum, N, E);
  k_fill<<<(E + 255) / 256, 256, 0, stream>>>(ei, ea, cursor, recs, E);
  k_gather<<<(N + 3) / 4, 256, 0, stream>>>(offs, recs, e1, e2, (const u32*)xenc, agg, N);
  k_mlp1<<<gemm_blocks, 256, 0, stream>>>(agg, W1T, b1, hbuf, N);
  k_mlp2<<<gemm_blocks, 256, 0, stream>>>(hbuf, W2T, b2, out, N);
}

// Round 5
// 291.336 us; speedup vs baseline: 3.3967x; 1.0814x over previous
//
#include <hip/hip_runtime.h>

typedef unsigned short u16;
typedef unsigned int   u32;
typedef __attribute__((ext_vector_type(8))) short short8;   // 8 bf16 (4 VGPRs)
typedef __attribute__((ext_vector_type(4))) float f32x4;    // MFMA C/D

// ---- bf16 helpers (bf16 = top 16 bits of fp32; half-up rounding) ----
__device__ __forceinline__ float bl(u32 u){ union{u32 i; float f;} c; c.i = u << 16; return c.f; }
__device__ __forceinline__ float bh(u32 u){ union{u32 i; float f;} c; c.i = u & 0xffff0000u; return c.f; }
__device__ __forceinline__ u16 f2b(float f){
  union{float f; u32 i;} c; c.f = f;
  return (u16)((c.i + 0x8000u) >> 16);
}
__device__ __forceinline__ u32 pk2(float a, float b){
  union{float f; u32 i;} x, y; x.f = a; y.f = b;
  return ((x.i + 0x8000u) >> 16) | ((y.i + 0x8000u) & 0xffff0000u);
}

// =====================================================================
// k_prep: transpose weights to bf16 n-major  WT[n][k]
// =====================================================================
__global__ __launch_bounds__(256) void k_prep(
    const float* __restrict__ Wenc, const float* __restrict__ W1,
    const float* __restrict__ W2, u16* __restrict__ WencT,
    u16* __restrict__ W1T, u16* __restrict__ W2T)
{
  int i = blockIdx.x * 256 + threadIdx.x;
  if (i < 16384) {                       // WencT: [128 n][128 k]
    int n = i >> 7, k = i & 127;
    WencT[i] = f2b(Wenc[k * 128 + n]);
  } else if (i < 16384 + 32768) {        // W1T: [256 n][128 k]
    int j = i - 16384;
    int n = j >> 7, k = j & 127;
    W1T[j] = f2b(W1[k * 256 + n]);
  } else if (i < 16384 + 32768 + 32768) { // W2T: [128 n][256 k]
    int j = i - 49152;
    int n = j >> 8, k = j & 255;
    W2T[j] = f2b(W2[k * 128 + n]);
  }
}

// =====================================================================
// k_enc: xenc = bf16( PReLU(x) @ W_enc )    [N,128]
// =====================================================================
__global__ __launch_bounds__(256) void k_enc(
    const float* __restrict__ x, const float* __restrict__ pa,
    const u16* __restrict__ WT, u16* __restrict__ xenc, int N)
{
  const int K = 128, SK = 136, NT = 8;
  __shared__ u16 sB[128 * SK];           // 34 KB

  const int t = threadIdx.x;
  #pragma unroll
  for (int j = 0; j < 8; j++) {
    int i = t + 256 * j;
    int n = i >> 4, k8 = i & 15;
    *(uint4*)&sB[n * SK + k8 * 8] = *(const uint4*)&WT[n * K + k8 * 8];
  }
  __syncthreads();

  const float slope = pa[0];
  const int lane = t & 63, wave = t >> 6, quad = lane >> 4, l16 = lane & 15;
  const int m0 = blockIdx.x * 128 + wave * 32;
  if (m0 >= N) return;

  f32x4 acc[2][NT];
  #pragma unroll
  for (int mr = 0; mr < 2; mr++)
    #pragma unroll
    for (int nt = 0; nt < NT; nt++) acc[mr][nt] = (f32x4){0.f, 0.f, 0.f, 0.f};

  #pragma unroll
  for (int ks = 0; ks < 4; ks++) {
    const int k0 = ks * 32 + quad * 8;
    union { u32 u[4]; short8 s; } a[2];
    #pragma unroll
    for (int mr = 0; mr < 2; mr++) {
      int row = m0 + mr * 16 + l16; row = min(row, N - 1);
      const float4* ap = (const float4*)&x[(size_t)row * 128 + k0];
      float4 f0 = ap[0], f1 = ap[1];
      float v0 = f0.x > 0.f ? f0.x : slope * f0.x;
      float v1 = f0.y > 0.f ? f0.y : slope * f0.y;
      float v2 = f0.z > 0.f ? f0.z : slope * f0.z;
      float v3 = f0.w > 0.f ? f0.w : slope * f0.w;
      float v4 = f1.x > 0.f ? f1.x : slope * f1.x;
      float v5 = f1.y > 0.f ? f1.y : slope * f1.y;
      float v6 = f1.z > 0.f ? f1.z : slope * f1.z;
      float v7 = f1.w > 0.f ? f1.w : slope * f1.w;
      a[mr].u[0] = pk2(v0, v1); a[mr].u[1] = pk2(v2, v3);
      a[mr].u[2] = pk2(v4, v5); a[mr].u[3] = pk2(v6, v7);
    }
    #pragma unroll
    for (int nt = 0; nt < NT; nt++) {
      short8 b = *(const short8*)&sB[(nt * 16 + l16) * SK + k0];
      acc[0][nt] = __builtin_amdgcn_mfma_f32_16x16x32_bf16(a[0].s, b, acc[0][nt], 0, 0, 0);
      acc[1][nt] = __builtin_amdgcn_mfma_f32_16x16x32_bf16(a[1].s, b, acc[1][nt], 0, 0, 0);
    }
  }

  #pragma unroll
  for (int mr = 0; mr < 2; mr++)
    #pragma unroll
    for (int nt = 0; nt < NT; nt++) {
      int col = nt * 16 + l16;
      #pragma unroll
      for (int r = 0; r < 4; r++) {
        int row = m0 + mr * 16 + quad * 4 + r;
        if (row < N) xenc[(size_t)row * 128 + col] = f2b(acc[mr][nt][r]);
      }
    }
}

// =====================================================================
// CSR build
// =====================================================================
__global__ __launch_bounds__(256) void k_count(
    const int* __restrict__ ei, int* __restrict__ cnt, int E)
{
  int e = blockIdx.x * 256 + threadIdx.x;
  if (e < E) atomicAdd(&cnt[ei[E + e]], 1);
}

__global__ __launch_bounds__(256) void k_scan_block(
    const int* __restrict__ cnt, int* __restrict__ offs,
    int* __restrict__ bsum, int n)
{
  __shared__ int sS[256];
  const int b = blockIdx.x, t = threadIdx.x;
  const int i0 = b * 1024 + t * 4;
  int4 v = make_int4(0, 0, 0, 0);
  if (i0 + 3 < n) v = *(const int4*)&cnt[i0];
  else {
    if (i0     < n) v.x = cnt[i0];
    if (i0 + 1 < n) v.y = cnt[i0 + 1];
    if (i0 + 2 < n) v.z = cnt[i0 + 2];
  }
  int s = v.x + v.y + v.z + v.w;
  sS[t] = s;
  __syncthreads();
  for (int d = 1; d < 256; d <<= 1) {
    int val = (t >= d) ? sS[t - d] : 0;
    __syncthreads();
    sS[t] += val;
    __syncthreads();
  }
  int ex = sS[t] - s;
  if (t == 255) bsum[b] = sS[t];
  int o0 = ex, o1 = o0 + v.x, o2 = o1 + v.y, o3 = o2 + v.z;
  if (i0     < n) offs[i0]     = o0;
  if (i0 + 1 < n) offs[i0 + 1] = o1;
  if (i0 + 2 < n) offs[i0 + 2] = o2;
  if (i0 + 3 < n) offs[i0 + 3] = o3;
}

__global__ void k_scan_bsum(int* __restrict__ bsum, int nb)
{
  if (threadIdx.x == 0 && blockIdx.x == 0) {
    int acc = 0;
    for (int i = 0; i < nb; i++) { int t = bsum[i]; bsum[i] = acc; acc += t; }
  }
}

__global__ __launch_bounds__(256) void k_scan_add(
    int* __restrict__ offs, int* __restrict__ cursor,
    const int* __restrict__ bsum, int n, int E)
{
  int i = blockIdx.x * 256 + threadIdx.x;
  if (i < n) {
    int v = offs[i] + bsum[i >> 10];
    offs[i] = v;
    cursor[i] = v;
  }
  if (i == n) offs[n] = E;
}

__global__ __launch_bounds__(256) void k_fill(
    const int* __restrict__ ei, const int* __restrict__ ea,
    int* __restrict__ cursor, u32* __restrict__ recs, int E)
{
  int e = blockIdx.x * 256 + threadIdx.x;
  if (e >= E) return;
  int src = ei[e];
  int dst = ei[E + e];
  int2 a = *(const int2*)&ea[2 * e];
  int pos = atomicAdd(&cursor[dst], 1);
  recs[pos] = (u32)src | ((u32)(a.x * 6 + a.y) << 26);
}

// =====================================================================
// Gather: one wave per node, 2 feats/lane, edge loop unrolled x4 for MLP
// (memory-level parallelism). agg written once as packed bf16.
// =====================================================================
__global__ __launch_bounds__(256) void k_gather(
    const int* __restrict__ offs, const u32* __restrict__ recs,
    const float* __restrict__ e1, const float* __restrict__ e2,
    const u32* __restrict__ xenc32, u32* __restrict__ aggb, int N)
{
  __shared__ float2 sE[36 * 64];   // 18.4 KB

  const int t = threadIdx.x;
  for (int i = t; i < 36 * 64; i += 256) {
    int comb = i >> 6, l = i & 63;
    int c1 = comb / 6, c2 = comb - c1 * 6;
    float2 v1 = *(const float2*)&e1[c1 * 128 + 2 * l];
    float2 v2 = *(const float2*)&e2[c2 * 128 + 2 * l];
    sE[i] = make_float2(v1.x + v2.x, v1.y + v2.y);
  }
  __syncthreads();

  const int v = blockIdx.x * 4 + (t >> 6);
  if (v >= N) return;
  const int lane = t & 63;

  u32 xv = xenc32[(size_t)v * 64 + lane];
  float2 ec = sE[30 * 64 + lane];      // self-loop combo 5*6+0
  float a0 = bl(xv) + ec.x;
  float a1 = bh(xv) + ec.y;

  const int beg = offs[v], end = offs[v + 1];
  for (int base = beg; base < end; base += 64) {
    u32 rv = 0;
    if (base + lane < end) rv = recs[base + lane];
    const int cnt = min(64, end - base);
    int jj = 0;
    for (; jj + 4 <= cnt; jj += 4) {
      u32 r0 = __shfl(rv, jj + 0);
      u32 r1 = __shfl(rv, jj + 1);
      u32 r2 = __shfl(rv, jj + 2);
      u32 r3 = __shfl(rv, jj + 3);
      u32 x0 = xenc32[(size_t)(r0 & 0x3ffffffu) * 64 + lane];
      u32 x1 = xenc32[(size_t)(r1 & 0x3ffffffu) * 64 + lane];
      u32 x2 = xenc32[(size_t)(r2 & 0x3ffffffu) * 64 + lane];
      u32 x3 = xenc32[(size_t)(r3 & 0x3ffffffu) * 64 + lane];
      float2 e0 = sE[(r0 >> 26) * 64 + lane];
      float2 e1v = sE[(r1 >> 26) * 64 + lane];
      float2 e2v = sE[(r2 >> 26) * 64 + lane];
      float2 e3 = sE[(r3 >> 26) * 64 + lane];
      a0 += bl(x0) + e0.x;  a1 += bh(x0) + e0.y;
      a0 += bl(x1) + e1v.x; a1 += bh(x1) + e1v.y;
      a0 += bl(x2) + e2v.x; a1 += bh(x2) + e2v.y;
      a0 += bl(x3) + e3.x;  a1 += bh(x3) + e3.y;
    }
    for (; jj < cnt; jj++) {
      u32 r = __shfl(rv, jj);
      u32 x2 = xenc32[(size_t)(r & 0x3ffffffu) * 64 + lane];
      float2 e = sE[(r >> 26) * 64 + lane];
      a0 += bl(x2) + e.x;
      a1 += bh(x2) + e.y;
    }
  }
  aggb[(size_t)v * 64 + lane] = pk2(a0, a1);
}

// =====================================================================
// k_mlp1: h = bf16( silu(agg @ W1 + b1) )   [N,256], agg is bf16
// =====================================================================
__global__ __launch_bounds__(256) void k_mlp1(
    const u16* __restrict__ aggb, const u16* __restrict__ WT,
    const float* __restrict__ b1, u16* __restrict__ h, int N)
{
  const int K = 128, SK = 136, NT = 16;
  __shared__ u16   sB[256 * SK];       // 68 KB
  __shared__ float sBias[256];

  const int t = threadIdx.x;
  #pragma unroll
  for (int j = 0; j < 16; j++) {
    int i = t + 256 * j;
    int n = i >> 4, k8 = i & 15;
    *(uint4*)&sB[n * SK + k8 * 8] = *(const uint4*)&WT[n * K + k8 * 8];
  }
  if (t < 256) sBias[t] = b1[t];
  __syncthreads();

  const int lane = t & 63, wave = t >> 6, quad = lane >> 4, l16 = lane & 15;
  const int m0 = blockIdx.x * 128 + wave * 32;
  if (m0 >= N) return;

  f32x4 acc[2][NT];
  #pragma unroll
  for (int mr = 0; mr < 2; mr++)
    #pragma unroll
    for (int nt = 0; nt < NT; nt++) acc[mr][nt] = (f32x4){0.f, 0.f, 0.f, 0.f};

  #pragma unroll
  for (int ks = 0; ks < 4; ks++) {
    const int k0 = ks * 32 + quad * 8;
    union { uint4 q; short8 s; } a[2];
    #pragma unroll
    for (int mr = 0; mr < 2; mr++) {
      int row = m0 + mr * 16 + l16; row = min(row, N - 1);
      a[mr].q = *(const uint4*)&aggb[(size_t)row * 128 + k0];
    }
    #pragma unroll
    for (int nt = 0; nt < NT; nt++) {
      short8 b = *(const short8*)&sB[(nt * 16 + l16) * SK + k0];
      acc[0][nt] = __builtin_amdgcn_mfma_f32_16x16x32_bf16(a[0].s, b, acc[0][nt], 0, 0, 0);
      acc[1][nt] = __builtin_amdgcn_mfma_f32_16x16x32_bf16(a[1].s, b, acc[1][nt], 0, 0, 0);
    }
  }

  #pragma unroll
  for (int mr = 0; mr < 2; mr++)
    #pragma unroll
    for (int nt = 0; nt < NT; nt++) {
      int col = nt * 16 + l16;
      float bias = sBias[col];
      #pragma unroll
      for (int r = 0; r < 4; r++) {
        int row = m0 + mr * 16 + quad * 4 + r;
        if (row < N) {
          float z = acc[mr][nt][r] + bias;
          float s = z / (1.f + __expf(-z));
          h[(size_t)row * 256 + col] = f2b(s);
        }
      }
    }
}

// =====================================================================
// k_mlp2: out = h @ W2 + b2   [N,128] fp32
// =====================================================================
__global__ __launch_bounds__(256) void k_mlp2(
    const u16* __restrict__ h, const u16* __restrict__ WT,
    const float* __restrict__ b2, float* __restrict__ out, int N)
{
  const int K = 256, SK = 264, NT = 8;
  __shared__ u16   sB[128 * SK];       // 66 KB
  __shared__ float sBias[128];

  const int t = threadIdx.x;
  #pragma unroll
  for (int j = 0; j < 16; j++) {
    int i = t + 256 * j;
    int n = i >> 5, k8 = i & 31;
    *(uint4*)&sB[n * SK + k8 * 8] = *(const uint4*)&WT[n * K + k8 * 8];
  }
  if (t < 128) sBias[t] = b2[t];
  __syncthreads();

  const int lane = t & 63, wave = t >> 6, quad = lane >> 4, l16 = lane & 15;
  const int m0 = blockIdx.x * 128 + wave * 32;
  if (m0 >= N) return;

  f32x4 acc[2][NT];
  #pragma unroll
  for (int mr = 0; mr < 2; mr++)
    #pragma unroll
    for (int nt = 0; nt < NT; nt++) acc[mr][nt] = (f32x4){0.f, 0.f, 0.f, 0.f};

  #pragma unroll
  for (int ks = 0; ks < 8; ks++) {
    const int k0 = ks * 32 + quad * 8;
    union { uint4 q; short8 s; } a[2];
    #pragma unroll
    for (int mr = 0; mr < 2; mr++) {
      int row = m0 + mr * 16 + l16; row = min(row, N - 1);
      a[mr].q = *(const uint4*)&h[(size_t)row * 256 + k0];
    }
    #pragma unroll
    for (int nt = 0; nt < NT; nt++) {
      short8 b = *(const short8*)&sB[(nt * 16 + l16) * SK + k0];
      acc[0][nt] = __builtin_amdgcn_mfma_f32_16x16x32_bf16(a[0].s, b, acc[0][nt], 0, 0, 0);
      acc[1][nt] = __builtin_amdgcn_mfma_f32_16x16x32_bf16(a[1].s, b, acc[1][nt], 0, 0, 0);
    }
  }

  #pragma unroll
  for (int mr = 0; mr < 2; mr++)
    #pragma unroll
    for (int nt = 0; nt < NT; nt++) {
      int col = nt * 16 + l16;
      float bias = sBias[col];
      #pragma unroll
      for (int r = 0; r < 4; r++) {
        int row = m0 + mr * 16 + quad * 4 + r;
        if (row < N) out[(size_t)row * 128 + col] = acc[mr][nt][r] + bias;
      }
    }
}

// =====================================================================
extern "C" void kernel_launch(void* const* d_in, const int* in_sizes, int n_in,
                              void* d_out, int out_size, void* d_ws, size_t ws_size,
                              hipStream_t stream) {
  const float* x    = (const float*)d_in[0];
  const int*   ei   = (const int*)d_in[1];
  const int*   ea   = (const int*)d_in[2];
  const float* pa   = (const float*)d_in[3];
  const float* Wenc = (const float*)d_in[4];
  const float* e1   = (const float*)d_in[5];
  const float* e2   = (const float*)d_in[6];
  const float* W1   = (const float*)d_in[7];
  const float* b1   = (const float*)d_in[8];
  const float* W2   = (const float*)d_in[9];
  const float* b2   = (const float*)d_in[10];
  float* out = (float*)d_out;

  const int N = in_sizes[0] / 128;
  const int E = in_sizes[1] / 2;

  char* ws = (char*)d_ws;
  size_t off = 0;
  auto alloc = [&](size_t bytes) {
    void* p = ws + off;
    off = (off + bytes + 255) & ~(size_t)255;
    return p;
  };
  u16*   xenc   = (u16*)  alloc((size_t)N * 128 * 2);
  u32*   aggb   = (u32*)  alloc((size_t)N * 64 * 4);   // bf16 agg, packed
  u16*   hbuf   = (u16*)  alloc((size_t)N * 256 * 2);
  int*   cnt    = (int*)  alloc((size_t)N * 4);
  int*   offs   = (int*)  alloc((size_t)(N + 1) * 4);
  int*   cursor = (int*)  alloc((size_t)N * 4);
  int*   bsum   = (int*)  alloc(256 * 4);
  u32*   recs   = (u32*)  alloc((size_t)E * 4);
  u16*   WencT  = (u16*)  alloc(128 * 128 * 2);
  u16*   W1T    = (u16*)  alloc(256 * 128 * 2);
  u16*   W2T    = (u16*)  alloc(128 * 256 * 2);

  const int nb = (N + 1023) / 1024;
  const int gemm_blocks = (N + 127) / 128;

  hipMemsetAsync(cnt, 0, (size_t)N * 4, stream);
  k_prep<<<320, 256, 0, stream>>>(Wenc, W1, W2, WencT, W1T, W2T);
  k_enc<<<gemm_blocks, 256, 0, stream>>>(x, pa, WencT, xenc, N);
  k_count<<<(E + 255) / 256, 256, 0, stream>>>(ei, cnt, E);
  k_scan_block<<<nb, 256, 0, stream>>>(cnt, offs, bsum, N);
  k_scan_bsum<<<1, 64, 0, stream>>>(bsum, nb);
  k_scan_add<<<(N + 256) / 256, 256, 0, stream>>>(offs, cursor, bsum, N, E);
  k_fill<<<(E + 255) / 256, 256, 0, stream>>>(ei, ea, cursor, recs, E);
  k_gather<<<(N + 3) / 4, 256, 0, stream>>>(offs, recs, e1, e2, (const u32*)xenc, aggb, N);
  k_mlp1<<<gemm_blocks, 256, 0, stream>>>((const u16*)aggb, W1T, b1, hbuf, N);
  k_mlp2<<<gemm_blocks, 256, 0, stream>>>(hbuf, W2T, b2, out, N);
}